// Round 5
// baseline (109.879 us; speedup 1.0000x reference)
//
#include <hip/hip_runtime.h>
#include <hip/hip_bf16.h>
#include <stdint.h>

using bf16x8 = __attribute__((ext_vector_type(8))) short;
using f32x4  = __attribute__((ext_vector_type(4))) float;

#define N_NODES  50000
#define K1       768
#define D1       512
#define NPAIR    16384
#define NOUT     97
#define NOUT_PAD 112
#define MTILES   391                 // ceil(50000/128)
#define NTILES   4
#define NWG      (MTILES * NTILES)   // 1564
#define WGPX     196                 // ceil(1564/8)
#define KSTEPS   (K1 / 32)           // 24

__device__ __forceinline__ uint16_t f2bf(float f) {
    uint32_t u = __builtin_bit_cast(uint32_t, f);
    return (uint16_t)((u + 0x7fffu + ((u >> 16) & 1u)) >> 16);  // RNE
}

__device__ __forceinline__ uint32_t cvt_pk_bf16(float lo, float hi) {
    uint32_t r;
    asm("v_cvt_pk_bf16_f32 %0, %1, %2" : "=v"(r) : "v"(lo), "v"(hi));
    return r;
}

// async global->LDS DMA, 16B per lane; LDS dest = wave-uniform base + lane*16
__device__ __forceinline__ void gll16(const void* g, void* l) {
    __builtin_amdgcn_global_load_lds(
        (const __attribute__((address_space(1))) void*)g,
        (__attribute__((address_space(3))) void*)l, 16, 0, 0);
}

// ---- convert: W1[768][512] -> W1t bf16 [512][768]; Wp[1024][97] -> Wpt bf16 [112][1024] ----
__global__ void k_convert(const float* __restrict__ W1, const float* __restrict__ Wp,
                          uint16_t* __restrict__ W1t, uint16_t* __restrict__ Wpt) {
    int idx = blockIdx.x * 256 + threadIdx.x;
    const int n1 = D1 * K1;
    if (idx < n1) {
        int c = idx / K1, k = idx - c * K1;
        W1t[idx] = f2bf(W1[k * D1 + c]);
    } else {
        int j = idx - n1;
        if (j < NOUT_PAD * 1024) {
            int c = j >> 10, k = j & 1023;
            Wpt[j] = (c < NOUT) ? f2bf(Wp[k * NOUT + c]) : (uint16_t)0;
        }
    }
}

// ---- GEMM1: H[50000][512] = relu(A[50000][768] @ W1 + b1) ----
// 128x128 tile, BK=32, global_load_lds staging, DOUBLE-buffered LDS with
// counted vmcnt(6) (loads fly across one full compute phase; never drain to 0
// in the loop). A fp32 in LDS chunk-swizzled (^row&7); B bf16 chunk-swizzled
// (^ (row>>1)&3) -> both reads 2-way (free). XCD-grouped block order.
__global__ __launch_bounds__(256) void k_gemm1(const float* __restrict__ A,
        const uint16_t* __restrict__ W1t, const float* __restrict__ bias1,
        uint16_t* __restrict__ H) {
    __shared__ float    lds_a[2 * 4096];   // 2 x (128 rows x 32 fp32)
    __shared__ uint16_t lds_b[2 * 4096];   // 2 x (128 rows x 32 bf16)

    const int bid = blockIdx.x;
    const int tt = (bid & 7) * WGPX + (bid >> 3);
    if (tt >= NWG) return;
    const int m0 = (tt >> 2) * 128, n0 = (tt & 3) * 128;

    const int t = threadIdx.x, lane = t & 63, w = t >> 6;
    const int wm = w >> 1, wn = w & 1;
    const int cl = lane & 15, kh = lane >> 4;
    const int l3 = lane >> 3, l7 = lane & 7;

    // --- A staging: instr i covers rows w*32+i*8+(lane>>3), phys chunk lane&7.
    //     logical chunk = phys ^ (row&7) = l7 ^ l3 -> pre-swizzled source.
    const float* aSrc[4];
    #pragma unroll
    for (int i = 0; i < 4; ++i) {
        int r = m0 + w * 32 + i * 8 + l3;
        if (r >= N_NODES) r = N_NODES - 1;   // tail clamp (stores guarded)
        aSrc[i] = A + (size_t)r * K1 + ((l7 ^ l3) * 4);
    }
    // --- B staging: instr i covers rows w*32+i*16+(lane>>2), phys chunk lane&3.
    //     logical chunk = phys ^ ((row>>1)&3) = (lane&3) ^ ((lane>>3)&3).
    const uint16_t* bSrc[2];
    #pragma unroll
    for (int i = 0; i < 2; ++i)
        bSrc[i] = W1t + (size_t)(n0 + w * 32 + i * 16 + (lane >> 2)) * K1
                      + (((lane & 3) ^ ((lane >> 3) & 3)) * 8);

    float*    aDst = &lds_a[w * 1024];   // + buf*4096 + i*256 floats
    uint16_t* bDst = &lds_b[w * 1024];   // + buf*4096 + i*512 u16

    // --- fragment read offsets.
    // A: logical chunk c of row r at phys c ^ (r&7); r&7 == cl&7.
    const int q7 = cl & 7;
    const int pa0 = ((2 * kh) ^ q7) * 4, pa1 = ((2 * kh + 1) ^ q7) * 4;
    const int arow0 = (wm * 64 + cl) * 32;           // + m*512
    // B: logical chunk kh of row r at phys kh ^ ((r>>1)&3); (r>>1)&3 == (cl>>1)&3.
    const int brow0 = (wn * 64 + cl) * 32 + ((kh ^ ((cl >> 1) & 3)) * 8);  // + n*512

    f32x4 acc[4][4];
    const f32x4 z = {0.f, 0.f, 0.f, 0.f};
    #pragma unroll
    for (int m = 0; m < 4; ++m)
        #pragma unroll
        for (int n = 0; n < 4; ++n) acc[m][n] = z;

#define STAGE(BUF) do {                                                    \
    _Pragma("unroll")                                                      \
    for (int i = 0; i < 4; ++i) gll16(aSrc[i], aDst + (BUF) * 4096 + i * 256); \
    _Pragma("unroll")                                                      \
    for (int i = 0; i < 2; ++i) gll16(bSrc[i], bDst + (BUF) * 4096 + i * 512); \
    _Pragma("unroll")                                                      \
    for (int i = 0; i < 4; ++i) aSrc[i] += 32;                             \
    _Pragma("unroll")                                                      \
    for (int i = 0; i < 2; ++i) bSrc[i] += 32;                             \
    } while (0)

#define COMPUTE(BUF) do {                                                  \
    const float*    la = &lds_a[(BUF) * 4096];                             \
    const uint16_t* lb = &lds_b[(BUF) * 4096];                             \
    bf16x8 af[4], bfr[4];                                                  \
    _Pragma("unroll")                                                      \
    for (int n = 0; n < 4; ++n)                                            \
        bfr[n] = *(const bf16x8*)&lb[brow0 + n * 512];                     \
    _Pragma("unroll")                                                      \
    for (int m = 0; m < 4; ++m) {                                          \
        f32x4 r0 = *(const f32x4*)&la[arow0 + m * 512 + pa0];              \
        f32x4 r1 = *(const f32x4*)&la[arow0 + m * 512 + pa1];              \
        uint32_t uu[4];                                                    \
        uu[0] = cvt_pk_bf16(r0[0], r0[1]);                                 \
        uu[1] = cvt_pk_bf16(r0[2], r0[3]);                                 \
        uu[2] = cvt_pk_bf16(r1[0], r1[1]);                                 \
        uu[3] = cvt_pk_bf16(r1[2], r1[3]);                                 \
        af[m] = *(const bf16x8*)uu;                                        \
    }                                                                      \
    _Pragma("unroll")                                                      \
    for (int m = 0; m < 4; ++m)                                            \
        _Pragma("unroll")                                                  \
        for (int n = 0; n < 4; ++n)                                        \
            acc[m][n] = __builtin_amdgcn_mfma_f32_16x16x32_bf16(           \
                            af[m], bfr[n], acc[m][n], 0, 0, 0);            \
    } while (0)

    STAGE(0);   // prologue: K-step 0 in flight
    for (int kt = 0; kt < KSTEPS - 1; ++kt) {
        const int cur = kt & 1;
        STAGE(cur ^ 1);                                  // issue kt+1 (6 loads)
        asm volatile("s_waitcnt vmcnt(6)" ::: "memory"); // kt's 6 loads landed
        __builtin_amdgcn_s_barrier();                    // all waves: tile ready
        COMPUTE(cur);
        __builtin_amdgcn_s_barrier();                    // all reads done -> buf free
    }
    asm volatile("s_waitcnt vmcnt(0)" ::: "memory");     // last tile's loads
    __builtin_amdgcn_s_barrier();
    COMPUTE((KSTEPS - 1) & 1);

#undef STAGE
#undef COMPUTE

    // epilogue: +bias, relu, bf16 store.  C layout: col = lane&15, row = (lane>>4)*4 + reg
    float bv[4]; int bcol[4];
    #pragma unroll
    for (int n = 0; n < 4; ++n) { bcol[n] = n0 + wn * 64 + n * 16 + cl; bv[n] = bias1[bcol[n]]; }
    #pragma unroll
    for (int m = 0; m < 4; ++m) {
        int rbase = m0 + wm * 64 + m * 16 + kh * 4;
        #pragma unroll
        for (int rr = 0; rr < 4; ++rr) {
            int row = rbase + rr;
            if (row < N_NODES) {
                #pragma unroll
                for (int n = 0; n < 4; ++n) {
                    float v = acc[m][n][rr] + bv[n];
                    H[(size_t)row * D1 + bcol[n]] = f2bf(fmaxf(v, 0.f));
                }
            }
        }
    }
}

// ---- GEMM2: out[16384][97] = concat(H[head], H[tail]) @ Wp + bp ----
__global__ __launch_bounds__(256) void k_gemm2(const uint16_t* __restrict__ H,
        const uint16_t* __restrict__ Wpt, const float* __restrict__ bp,
        const int* __restrict__ head, const int* __restrict__ tail,
        float* __restrict__ out) {
    __shared__ uint16_t lds_w[NOUT_PAD][40];
    const int t = threadIdx.x;
    const int lane = t & 63, wave = t >> 6;
    const int cl = lane & 15, kh = lane >> 4;
    const int rowbase = blockIdx.x * 64 + wave * 16;
    const int i_l = rowbase + cl;
    const int nodeH = head[i_l], nodeT = tail[i_l];
    const uint16_t* hH = H + (size_t)nodeH * D1 + kh * 8;
    const uint16_t* hT = H + (size_t)nodeT * D1 + kh * 8;

    f32x4 acc[7];
    const f32x4 z = {0.f, 0.f, 0.f, 0.f};
    #pragma unroll
    for (int n = 0; n < 7; ++n) acc[n] = z;

    const int wrow = t >> 1, whalf = t & 1;
    const uint16_t* wsrc = Wpt + (size_t)wrow * 1024 + whalf * 16;
    uint16_t* wdst = &lds_w[wrow][whalf * 16];

    for (int kb = 0; kb < 32; ++kb) {
        uint4 w0 = {0,0,0,0}, w1 = {0,0,0,0};
        if (t < 224) {
            const uint4* wp4 = (const uint4*)(wsrc + kb * 32);
            w0 = wp4[0]; w1 = wp4[1];
        }
        bf16x8 af = (kb < 16) ? *(const bf16x8*)(hH + kb * 32)
                              : *(const bf16x8*)(hT + (kb - 16) * 32);
        __syncthreads();
        if (t < 224) { ((uint4*)wdst)[0] = w0; ((uint4*)wdst)[1] = w1; }
        __syncthreads();
        #pragma unroll
        for (int n = 0; n < 7; ++n) {
            bf16x8 bfr = *(const bf16x8*)&lds_w[n * 16 + cl][kh * 8];
            acc[n] = __builtin_amdgcn_mfma_f32_16x16x32_bf16(af, bfr, acc[n], 0, 0, 0);
        }
    }
    #pragma unroll
    for (int n = 0; n < 7; ++n) {
        int col = n * 16 + cl;
        if (col < NOUT) {
            float bb = bp[col];
            #pragma unroll
            for (int rr = 0; rr < 4; ++rr) {
                int i = rowbase + kh * 4 + rr;
                out[(size_t)i * NOUT + col] = acc[n][rr] + bb;
            }
        }
    }
}

extern "C" void kernel_launch(void* const* d_in, const int* in_sizes, int n_in,
                              void* d_out, int out_size, void* d_ws, size_t ws_size,
                              hipStream_t stream) {
    const float* node_features = (const float*)d_in[0];
    // d_in[1] = edge_features (unused: message passing is an exact identity)
    const float* W1   = (const float*)d_in[2];
    const float* b1   = (const float*)d_in[3];
    const float* Wp   = (const float*)d_in[4];
    const float* bp   = (const float*)d_in[5];
    // d_in[6] = src (unused), d_in[7] = dst (unused)
    const int* head   = (const int*)d_in[8];
    const int* tail   = (const int*)d_in[9];
    float* out = (float*)d_out;

    char* ws = (char*)d_ws;
    uint16_t* H   = (uint16_t*)ws;
    uint16_t* W1t = (uint16_t*)(ws + (size_t)N_NODES * D1 * 2);
    uint16_t* Wpt = (uint16_t*)(ws + (size_t)N_NODES * D1 * 2 + (size_t)D1 * K1 * 2);

    const int convN = D1 * K1 + NOUT_PAD * 1024;
    k_convert<<<(convN + 255) / 256, 256, 0, stream>>>(W1, Wp, W1t, Wpt);

    k_gemm1<<<WGPX * 8, 256, 0, stream>>>(node_features, W1t, b1, H);

    k_gemm2<<<NPAIR / 64, 256, 0, stream>>>(H, Wpt, bp, head, tail, out);
}

// Round 6
// 99.754 us; speedup vs baseline: 1.1015x; 1.1015x over previous
//
#include <hip/hip_runtime.h>
#include <hip/hip_bf16.h>
#include <stdint.h>

using bf16x8 = __attribute__((ext_vector_type(8))) short;
using f32x4  = __attribute__((ext_vector_type(4))) float;

#define N_NODES  50000
#define K1       768
#define D1       512
#define NPAIR    16384
#define NOUT     97
#define NOUT_PAD 112
#define MTILES   391                 // ceil(50000/128)
#define NTILES   4
#define NWG      (MTILES * NTILES)   // 1564
#define WGPX     196                 // ceil(1564/8)
#define KSTEPS   (K1 / 32)           // 24

__device__ __forceinline__ uint16_t f2bf(float f) {
    uint32_t u = __builtin_bit_cast(uint32_t, f);
    return (uint16_t)((u + 0x7fffu + ((u >> 16) & 1u)) >> 16);  // RNE
}

__device__ __forceinline__ uint32_t cvt_pk_bf16(float lo, float hi) {
    uint32_t r;
    asm("v_cvt_pk_bf16_f32 %0, %1, %2" : "=v"(r) : "v"(lo), "v"(hi));
    return r;
}

// async global->LDS DMA, 16B per lane; LDS dest = wave-uniform base + lane*16
__device__ __forceinline__ void gll16(const void* g, void* l) {
    __builtin_amdgcn_global_load_lds(
        (const __attribute__((address_space(1))) void*)g,
        (__attribute__((address_space(3))) void*)l, 16, 0, 0);
}

// ---- convert: W1[768][512] -> W1t bf16 [512][768]; Wp[1024][97] -> Wpt bf16 [112][1024] ----
__global__ void k_convert(const float* __restrict__ W1, const float* __restrict__ Wp,
                          uint16_t* __restrict__ W1t, uint16_t* __restrict__ Wpt) {
    int idx = blockIdx.x * 256 + threadIdx.x;
    const int n1 = D1 * K1;
    if (idx < n1) {
        int c = idx / K1, k = idx - c * K1;
        W1t[idx] = f2bf(W1[k * D1 + c]);
    } else {
        int j = idx - n1;
        if (j < NOUT_PAD * 1024) {
            int c = j >> 10, k = j & 1023;
            Wpt[j] = (c < NOUT) ? f2bf(Wp[k * NOUT + c]) : (uint16_t)0;
        }
    }
}

// ---- GEMM1: H[50000][512] = relu(A[50000][768] @ W1 + b1) ----
// 128x128 tile, BK=32, EIGHT waves (4wm x 2wn) for TLP: per-wave acc = 2x4
// fragments (32 AGPR). global_load_lds staging, double-buffered LDS, counted
// vmcnt(3). A fp32 chunk-swizzled (^row&7); B bf16 chunk-swizzled (^(row>>1)&3).
__global__ __launch_bounds__(512) void k_gemm1(const float* __restrict__ A,
        const uint16_t* __restrict__ W1t, const float* __restrict__ bias1,
        uint16_t* __restrict__ H) {
    __shared__ float    lds_a[2 * 4096];   // 2 x (128 rows x 32 fp32)  = 32KB
    __shared__ uint16_t lds_b[2 * 4096];   // 2 x (128 rows x 32 bf16)  = 16KB

    const int bid = blockIdx.x;
    const int tt = (bid & 7) * WGPX + (bid >> 3);
    if (tt >= NWG) return;
    const int m0 = (tt >> 2) * 128, n0 = (tt & 3) * 128;

    const int t = threadIdx.x, lane = t & 63, w = t >> 6;
    const int wm = w >> 1, wn = w & 1;            // 4 x 2 wave grid
    const int cl = lane & 15, kh = lane >> 4;

    // --- A staging: instr i (i=0,1) covers rows i*64 + (t>>3), phys chunk t&7.
    //     logical chunk = phys ^ (row&7) = (t&7) ^ ((t>>3)&7)  (source pre-swizzle)
    const float* aSrc[2];
    #pragma unroll
    for (int i = 0; i < 2; ++i) {
        int r = m0 + i * 64 + (t >> 3);
        if (r >= N_NODES) r = N_NODES - 1;   // tail clamp (stores guarded)
        aSrc[i] = A + (size_t)r * K1 + (((t & 7) ^ ((t >> 3) & 7)) * 4);
    }
    // --- B staging: covers rows t>>2, phys chunk t&3.
    //     logical chunk = phys ^ ((row>>1)&3) = (t&3) ^ ((t>>3)&3)
    const uint16_t* bSrc =
        W1t + (size_t)(n0 + (t >> 2)) * K1 + (((t & 3) ^ ((t >> 3) & 3)) * 8);

    float*    aDst = &lds_a[w * 256];   // + buf*4096 + i*2048 floats
    uint16_t* bDst = &lds_b[w * 512];   // + buf*4096 u16

    // --- fragment read offsets.
    // A: row = wm*32 + mf*16 + cl; row&7 == cl&7; logical chunk c at phys c^(row&7)
    const int q7 = cl & 7;
    const int pa0 = ((2 * kh) ^ q7) * 4, pa1 = ((2 * kh + 1) ^ q7) * 4;
    const int arow0 = (wm * 32 + cl) * 32;           // + mf*512
    // B: row = wn*64 + nf*16 + cl; (row>>1)&3 == (cl>>1)&3
    const int brow0 = (wn * 64 + cl) * 32 + ((kh ^ ((cl >> 1) & 3)) * 8);  // + nf*512

    f32x4 acc[2][4];
    const f32x4 z = {0.f, 0.f, 0.f, 0.f};
    #pragma unroll
    for (int m = 0; m < 2; ++m)
        #pragma unroll
        for (int n = 0; n < 4; ++n) acc[m][n] = z;

#define STAGE(BUF) do {                                                        \
    gll16(aSrc[0], aDst + (BUF) * 4096);                                       \
    gll16(aSrc[1], aDst + (BUF) * 4096 + 2048);                                \
    gll16(bSrc,    bDst + (BUF) * 4096);                                       \
    aSrc[0] += 32; aSrc[1] += 32; bSrc += 32;                                  \
    } while (0)

#define COMPUTE(BUF) do {                                                      \
    const float*    la = &lds_a[(BUF) * 4096];                                 \
    const uint16_t* lb = &lds_b[(BUF) * 4096];                                 \
    bf16x8 bfr[4];                                                             \
    _Pragma("unroll")                                                          \
    for (int n = 0; n < 4; ++n)                                                \
        bfr[n] = *(const bf16x8*)&lb[brow0 + n * 512];                         \
    _Pragma("unroll")                                                          \
    for (int m = 0; m < 2; ++m) {                                              \
        f32x4 r0 = *(const f32x4*)&la[arow0 + m * 512 + pa0];                  \
        f32x4 r1 = *(const f32x4*)&la[arow0 + m * 512 + pa1];                  \
        uint32_t uu[4];                                                        \
        uu[0] = cvt_pk_bf16(r0[0], r0[1]);                                     \
        uu[1] = cvt_pk_bf16(r0[2], r0[3]);                                     \
        uu[2] = cvt_pk_bf16(r1[0], r1[1]);                                     \
        uu[3] = cvt_pk_bf16(r1[2], r1[3]);                                     \
        bf16x8 af = *(const bf16x8*)uu;                                        \
        _Pragma("unroll")                                                      \
        for (int n = 0; n < 4; ++n)                                            \
            acc[m][n] = __builtin_amdgcn_mfma_f32_16x16x32_bf16(               \
                            af, bfr[n], acc[m][n], 0, 0, 0);                   \
    }                                                                          \
    } while (0)

    STAGE(0);   // prologue: K-step 0 in flight (3 loads outstanding)
    for (int kt = 0; kt < KSTEPS - 1; ++kt) {
        const int cur = kt & 1;
        STAGE(cur ^ 1);                                  // issue kt+1 (3 loads)
        asm volatile("s_waitcnt vmcnt(3)" ::: "memory"); // kt's 3 loads landed
        __builtin_amdgcn_s_barrier();                    // all waves: tile ready
        COMPUTE(cur);
        __builtin_amdgcn_s_barrier();                    // reads done -> buf free
    }
    asm volatile("s_waitcnt vmcnt(0)" ::: "memory");
    __builtin_amdgcn_s_barrier();
    COMPUTE((KSTEPS - 1) & 1);

#undef STAGE
#undef COMPUTE

    // epilogue: +bias, relu, bf16 store.  C layout: col = lane&15, row = (lane>>4)*4 + reg
    float bv[4]; int bcol[4];
    #pragma unroll
    for (int n = 0; n < 4; ++n) { bcol[n] = n0 + wn * 64 + n * 16 + cl; bv[n] = bias1[bcol[n]]; }
    #pragma unroll
    for (int m = 0; m < 2; ++m) {
        int rbase = m0 + wm * 32 + m * 16 + kh * 4;
        #pragma unroll
        for (int rr = 0; rr < 4; ++rr) {
            int row = rbase + rr;
            if (row < N_NODES) {
                #pragma unroll
                for (int n = 0; n < 4; ++n) {
                    float v = acc[m][n][rr] + bv[n];
                    H[(size_t)row * D1 + bcol[n]] = f2bf(fmaxf(v, 0.f));
                }
            }
        }
    }
}

// ---- GEMM2: out[16384][97] = concat(H[head], H[tail]) @ Wp + bp ----
__global__ __launch_bounds__(256) void k_gemm2(const uint16_t* __restrict__ H,
        const uint16_t* __restrict__ Wpt, const float* __restrict__ bp,
        const int* __restrict__ head, const int* __restrict__ tail,
        float* __restrict__ out) {
    __shared__ uint16_t lds_w[NOUT_PAD][40];
    const int t = threadIdx.x;
    const int lane = t & 63, wave = t >> 6;
    const int cl = lane & 15, kh = lane >> 4;
    const int rowbase = blockIdx.x * 64 + wave * 16;
    const int i_l = rowbase + cl;
    const int nodeH = head[i_l], nodeT = tail[i_l];
    const uint16_t* hH = H + (size_t)nodeH * D1 + kh * 8;
    const uint16_t* hT = H + (size_t)nodeT * D1 + kh * 8;

    f32x4 acc[7];
    const f32x4 z = {0.f, 0.f, 0.f, 0.f};
    #pragma unroll
    for (int n = 0; n < 7; ++n) acc[n] = z;

    const int wrow = t >> 1, whalf = t & 1;
    const uint16_t* wsrc = Wpt + (size_t)wrow * 1024 + whalf * 16;
    uint16_t* wdst = &lds_w[wrow][whalf * 16];

    for (int kb = 0; kb < 32; ++kb) {
        uint4 w0 = {0,0,0,0}, w1 = {0,0,0,0};
        if (t < 224) {
            const uint4* wp4 = (const uint4*)(wsrc + kb * 32);
            w0 = wp4[0]; w1 = wp4[1];
        }
        bf16x8 af = (kb < 16) ? *(const bf16x8*)(hH + kb * 32)
                              : *(const bf16x8*)(hT + (kb - 16) * 32);
        __syncthreads();
        if (t < 224) { ((uint4*)wdst)[0] = w0; ((uint4*)wdst)[1] = w1; }
        __syncthreads();
        #pragma unroll
        for (int n = 0; n < 7; ++n) {
            bf16x8 bfr = *(const bf16x8*)&lds_w[n * 16 + cl][kh * 8];
            acc[n] = __builtin_amdgcn_mfma_f32_16x16x32_bf16(af, bfr, acc[n], 0, 0, 0);
        }
    }
    #pragma unroll
    for (int n = 0; n < 7; ++n) {
        int col = n * 16 + cl;
        if (col < NOUT) {
            float bb = bp[col];
            #pragma unroll
            for (int rr = 0; rr < 4; ++rr) {
                int i = rowbase + kh * 4 + rr;
                out[(size_t)i * NOUT + col] = acc[n][rr] + bb;
            }
        }
    }
}

extern "C" void kernel_launch(void* const* d_in, const int* in_sizes, int n_in,
                              void* d_out, int out_size, void* d_ws, size_t ws_size,
                              hipStream_t stream) {
    const float* node_features = (const float*)d_in[0];
    // d_in[1] = edge_features (unused: message passing is an exact identity)
    const float* W1   = (const float*)d_in[2];
    const float* b1   = (const float*)d_in[3];
    const float* Wp   = (const float*)d_in[4];
    const float* bp   = (const float*)d_in[5];
    // d_in[6] = src (unused), d_in[7] = dst (unused)
    const int* head   = (const int*)d_in[8];
    const int* tail   = (const int*)d_in[9];
    float* out = (float*)d_out;

    char* ws = (char*)d_ws;
    uint16_t* H   = (uint16_t*)ws;
    uint16_t* W1t = (uint16_t*)(ws + (size_t)N_NODES * D1 * 2);
    uint16_t* Wpt = (uint16_t*)(ws + (size_t)N_NODES * D1 * 2 + (size_t)D1 * K1 * 2);

    const int convN = D1 * K1 + NOUT_PAD * 1024;
    k_convert<<<(convN + 255) / 256, 256, 0, stream>>>(W1, Wp, W1t, Wpt);

    k_gemm1<<<WGPX * 8, 512, 0, stream>>>(node_features, W1t, b1, H);

    k_gemm2<<<NPAIR / 64, 256, 0, stream>>>(H, Wpt, bp, head, tail, out);
}